// Round 1
// baseline (1356.857 us; speedup 1.0000x reference)
//
#include <hip/hip_runtime.h>

#define DEVINL __device__ __forceinline__

// Exact (no-FMA-contraction) squared distance in the same rounding order as
// numpy/jax fp32: ((dx*dx + dy*dy) + dz*dz). Discrete decisions (FPS argmax,
// ball-query radius compare) depend on bit-exactness.
DEVINL float sq3(float ax, float ay, float az, float bx, float by, float bz) {
  float dx = __fsub_rn(ax, bx), dy = __fsub_rn(ay, by), dz = __fsub_rn(az, bz);
  return __fadd_rn(__fadd_rn(__fmul_rn(dx, dx), __fmul_rn(dy, dy)), __fmul_rn(dz, dz));
}

// ---------------------------------------------------------------------------
// K1: farthest point sampling. One block per batch (32), 256 threads.
// xyz staged in LDS (SoA). 512 sequential steps; per step: min-update of the
// running distance (8 points/lane) + first-occurrence argmax reduction.
// ---------------------------------------------------------------------------
__global__ __launch_bounds__(256) void k_fps(const float* __restrict__ xyz,
                                             int* __restrict__ fidx) {
  const int b = blockIdx.x, t = threadIdx.x;
  __shared__ float xs[2048], ys[2048], zs[2048];
  __shared__ int s_far;
  __shared__ float rv[4];
  __shared__ int ri[4];
  const float* P = xyz + (size_t)b * 6144;
  for (int i = t; i < 2048; i += 256) {
    xs[i] = P[3 * i]; ys[i] = P[3 * i + 1]; zs[i] = P[3 * i + 2];
  }
  if (t == 0) s_far = 0;
  float dist[8];
#pragma unroll
  for (int j = 0; j < 8; ++j) dist[j] = 1e10f;
  __syncthreads();
  int* out = fidx + b * 512;
  for (int it = 0; it < 512; ++it) {
    const int far = s_far;
    if (t == 0) out[it] = far;  // emit BEFORE update (scan emits carry's far)
    const float cx = xs[far], cy = ys[far], cz = zs[far];
    float bv = -1.0f;
    int bi = 0;
#pragma unroll
    for (int j = 0; j < 8; ++j) {
      const int idx = j * 256 + t;
      const float d = sq3(xs[idx], ys[idx], zs[idx], cx, cy, cz);
      const float nd = fminf(dist[j], d);
      dist[j] = nd;
      if (nd > bv) { bv = nd; bi = idx; }  // strict > keeps smallest idx (j asc)
    }
    // wave argmax, ties -> smaller index (jnp.argmax first-occurrence)
#pragma unroll
    for (int off = 1; off < 64; off <<= 1) {
      const float ov = __shfl_xor(bv, off);
      const int oi = __shfl_xor(bi, off);
      if (ov > bv || (ov == bv && oi < bi)) { bv = ov; bi = oi; }
    }
    if ((t & 63) == 0) { rv[t >> 6] = bv; ri[t >> 6] = bi; }
    __syncthreads();
    if (t == 0) {
      float v = rv[0];
      int i0 = ri[0];
#pragma unroll
      for (int w = 1; w < 4; ++w) {
        const float v2 = rv[w];
        const int i2 = ri[w];
        if (v2 > v || (v2 == v && i2 < i0)) { v = v2; i0 = i2; }
      }
      s_far = i0;
    }
    __syncthreads();
  }
}

// ---------------------------------------------------------------------------
// K2: ball query. One wave per centroid (16384 waves). Collect first 32
// ascending indices with d2 <= r^2; pad with first hit. Also writes new_xyz.
// ---------------------------------------------------------------------------
__global__ __launch_bounds__(256) void k_ballq(const float* __restrict__ xyz,
                                               const int* __restrict__ fidx,
                                               float* __restrict__ new_xyz,
                                               int* __restrict__ gidx) {
  const int gw = (blockIdx.x * 256 + threadIdx.x) >> 6;  // centroid id
  const int lane = threadIdx.x & 63;
  const int b = gw >> 9;
  const float* P = xyz + (size_t)b * 6144;
  const int cidx = fidx[gw];
  const float cx = P[3 * cidx], cy = P[3 * cidx + 1], cz = P[3 * cidx + 2];
  if (lane < 3) new_xyz[(size_t)gw * 3 + lane] = P[3 * cidx + lane];
  int* g = gidx + (size_t)gw * 32;
  int base = 0, firstidx = -1;
  for (int c0 = 0; c0 < 2048; c0 += 64) {
    const int idx = c0 + lane;
    const float d = sq3(cx, cy, cz, P[3 * idx], P[3 * idx + 1], P[3 * idx + 2]);
    const bool in = !(d > 0.04f);  // matches: exclude where sqr > r*r
    const unsigned long long m = __ballot(in);
    if (firstidx < 0 && m) firstidx = c0 + (int)__builtin_ctzll(m);
    if (in) {
      const int pos = base + (int)__popcll(m & ((1ull << lane) - 1ull));
      if (pos < 32) g[pos] = idx;
    }
    base += (int)__popcll(m);
    if (base >= 32) break;  // wave-uniform
  }
  for (int pos = base + lane; pos < 32; pos += 64) g[pos] = firstidx;
}

// ---------------------------------------------------------------------------
// K3: SA1 fused MLP (3->64->64->128) + max over 32 samples/group.
// lane = one grouped point; h0[64] regs; streaming d1-loop accumulates
// layer2 into acc[128] regs (all reg indices compile-time). Weights broadcast
// from LDS (uniform address => conflict-free broadcast reads).
// Block = 256 threads = 8 groups. Grid = 2048.
// ---------------------------------------------------------------------------
__global__ __launch_bounds__(256, 2) void k_sa1(
    const float* __restrict__ xyz, const float* __restrict__ new_xyz,
    const int* __restrict__ gidx, const float* __restrict__ w0,
    const float* __restrict__ b0, const float* __restrict__ w1,
    const float* __restrict__ b1, const float* __restrict__ w2,
    const float* __restrict__ b2, float* __restrict__ l1p) {
  __shared__ float sW0[64 * 4];    // packed row: w.x,w.y,w.z,bias
  __shared__ float sW1[64 * 64];   // row-major [d][c]
  __shared__ float sB1[64];
  __shared__ float sW2T[64 * 128];  // transposed [d1][e]
  __shared__ float sB2[128];
  const int t = threadIdx.x;
  for (int i = t; i < 64; i += 256) {
    sW0[4 * i] = w0[3 * i]; sW0[4 * i + 1] = w0[3 * i + 1];
    sW0[4 * i + 2] = w0[3 * i + 2]; sW0[4 * i + 3] = b0[i];
  }
  for (int i = t; i < 4096; i += 256) sW1[i] = w1[i];
  if (t < 64) sB1[t] = b1[t];
  for (int i = t; i < 8192; i += 256) sW2T[(i & 63) * 128 + (i >> 6)] = w2[i];
  if (t < 128) sB2[t] = b2[t];
  __syncthreads();
  const int p = blockIdx.x * 256 + t;  // global sample id
  const int g = p >> 5;                // group id = b*512+si
  const int b = p >> 14;
  const int lane = t & 63;
  const int src = gidx[p];
  const float* P = xyz + (size_t)b * 6144;
  const float nx = new_xyz[(size_t)g * 3], ny = new_xyz[(size_t)g * 3 + 1],
              nz = new_xyz[(size_t)g * 3 + 2];
  const float x = P[3 * src] - nx, y = P[3 * src + 1] - ny, z = P[3 * src + 2] - nz;
  float h0[64];
#pragma unroll
  for (int d = 0; d < 64; ++d) {
    const float4 w = ((const float4*)sW0)[d];
    h0[d] = fmaxf(0.0f, fmaf(w.x, x, fmaf(w.y, y, fmaf(w.z, z, w.w))));
  }
  float acc[128];
#pragma unroll
  for (int e4 = 0; e4 < 32; ++e4) {
    const float4 bb = ((const float4*)sB2)[e4];
    acc[4 * e4] = bb.x; acc[4 * e4 + 1] = bb.y;
    acc[4 * e4 + 2] = bb.z; acc[4 * e4 + 3] = bb.w;
  }
  for (int d1 = 0; d1 < 64; ++d1) {  // dynamic loop: layer1 scalar + layer2 rank-1 update
    const float4* wr = (const float4*)(sW1 + (d1 << 6));
    float s0 = 0.f, s1 = 0.f, s2 = 0.f, s3 = 0.f;
#pragma unroll
    for (int c4 = 0; c4 < 16; ++c4) {
      const float4 w = wr[c4];
      s0 = fmaf(w.x, h0[4 * c4], s0);
      s1 = fmaf(w.y, h0[4 * c4 + 1], s1);
      s2 = fmaf(w.z, h0[4 * c4 + 2], s2);
      s3 = fmaf(w.w, h0[4 * c4 + 3], s3);
    }
    const float s = fmaxf(0.0f, sB1[d1] + ((s0 + s1) + (s2 + s3)));
    const float4* w2r = (const float4*)(sW2T + (d1 << 7));
#pragma unroll
    for (int e4 = 0; e4 < 32; ++e4) {
      const float4 w = w2r[e4];
      acc[4 * e4] = fmaf(s, w.x, acc[4 * e4]);
      acc[4 * e4 + 1] = fmaf(s, w.y, acc[4 * e4 + 1]);
      acc[4 * e4 + 2] = fmaf(s, w.z, acc[4 * e4 + 2]);
      acc[4 * e4 + 3] = fmaf(s, w.w, acc[4 * e4 + 3]);
    }
  }
  // relu + max over each 32-lane half (one group) + predicated store
  float* outg = l1p + (size_t)g * 128;
#pragma unroll
  for (int e = 0; e < 128; ++e) {
    float v = fmaxf(0.0f, acc[e]);
    v = fmaxf(v, __shfl_xor(v, 1));
    v = fmaxf(v, __shfl_xor(v, 2));
    v = fmaxf(v, __shfl_xor(v, 4));
    v = fmaxf(v, __shfl_xor(v, 8));
    v = fmaxf(v, __shfl_xor(v, 16));
    if ((lane & 31) == (e & 31)) outg[e] = v;
  }
}

// ---------------------------------------------------------------------------
// SA2 layer kernels: lane = point (m), W chunk (32 output dims) staged in
// LDS, A row in registers. Outputs written transposed [d][m] (coalesced).
// ---------------------------------------------------------------------------
__global__ __launch_bounds__(256, 2) void k_sa2_l0(
    const float* __restrict__ new_xyz, const float* __restrict__ l1p,
    const float* __restrict__ w0, const float* __restrict__ b0,
    float* __restrict__ h0t) {
  __shared__ float sW[32 * 136];  // row: [0..2]=xyz w, [4..131]=feat w (16B aligned)
  __shared__ float sb[32];
  const int pb = blockIdx.x >> 2, ds = blockIdx.x & 3;
  const int t = threadIdx.x;
  const int d0 = ds * 32;
  for (int i = t; i < 32 * 131; i += 256) {
    const int r = i / 131, c = i - r * 131;
    const int dst = (c < 3) ? c : (c + 1);
    sW[r * 136 + dst] = w0[(size_t)(d0 + r) * 131 + c];
  }
  if (t < 32) sb[t] = b0[d0 + t];
  __syncthreads();
  const int m = pb * 256 + t;
  const float ax = new_xyz[(size_t)m * 3], ay = new_xyz[(size_t)m * 3 + 1],
              az = new_xyz[(size_t)m * 3 + 2];
  float4 av[32];
  const float4* lp = (const float4*)(l1p + (size_t)m * 128);
#pragma unroll
  for (int i = 0; i < 32; ++i) av[i] = lp[i];
  for (int dd = 0; dd < 32; ++dd) {
    const float* wr = sW + dd * 136;
    float s = fmaf(wr[0], ax, fmaf(wr[1], ay, fmaf(wr[2], az, sb[dd])));
    const float4* w4 = (const float4*)(wr + 4);
    float s0 = 0.f, s1 = 0.f, s2 = 0.f, s3 = 0.f;
#pragma unroll
    for (int i = 0; i < 32; ++i) {
      const float4 w = w4[i];
      s0 = fmaf(w.x, av[i].x, s0);
      s1 = fmaf(w.y, av[i].y, s1);
      s2 = fmaf(w.z, av[i].z, s2);
      s3 = fmaf(w.w, av[i].w, s3);
    }
    s += (s0 + s1) + (s2 + s3);
    h0t[(size_t)(d0 + dd) * 16384 + m] = fmaxf(0.0f, s);
  }
}

__global__ __launch_bounds__(256, 2) void k_sa2_l1(
    const float* __restrict__ h0t, const float* __restrict__ w1,
    const float* __restrict__ b1, float* __restrict__ h1t) {
  __shared__ float sW[32 * 128];
  __shared__ float sb[32];
  const int pb = blockIdx.x >> 2, ds = blockIdx.x & 3;
  const int t = threadIdx.x;
  const int d0 = ds * 32;
  for (int i = t; i < 32 * 128; i += 256) sW[i] = w1[(size_t)d0 * 128 + i];
  if (t < 32) sb[t] = b1[d0 + t];
  __syncthreads();
  const int m = pb * 256 + t;
  float a[128];
#pragma unroll
  for (int c = 0; c < 128; ++c) a[c] = h0t[(size_t)c * 16384 + m];
  for (int dd = 0; dd < 32; ++dd) {
    const float4* w4 = (const float4*)(sW + (dd << 7));
    float s0 = 0.f, s1 = 0.f, s2 = 0.f, s3 = 0.f;
#pragma unroll
    for (int i = 0; i < 32; ++i) {
      const float4 w = w4[i];
      s0 = fmaf(w.x, a[4 * i], s0);
      s1 = fmaf(w.y, a[4 * i + 1], s1);
      s2 = fmaf(w.z, a[4 * i + 2], s2);
      s3 = fmaf(w.w, a[4 * i + 3], s3);
    }
    h1t[(size_t)(d0 + dd) * 16384 + m] = fmaxf(0.0f, sb[dd] + ((s0 + s1) + (s2 + s3)));
  }
}

__global__ __launch_bounds__(256, 2) void k_sa2_l2max(
    const float* __restrict__ h1t, const float* __restrict__ w2,
    const float* __restrict__ b2, float* __restrict__ pmax) {
  __shared__ float sW[32 * 128];
  __shared__ float sb[32];
  const int pb = blockIdx.x >> 3, ds = blockIdx.x & 7;
  const int t = threadIdx.x;
  const int d0 = ds * 32;
  for (int i = t; i < 32 * 128; i += 256) sW[i] = w2[(size_t)d0 * 128 + i];
  if (t < 32) sb[t] = b2[d0 + t];
  __syncthreads();
  const int m = pb * 256 + t;
  const int b = m >> 9;
  const int wc = ((pb << 2) + (t >> 6)) & 7;  // wave-chunk within batch (0..7)
  const int lane = t & 63;
  float a[128];
#pragma unroll
  for (int c = 0; c < 128; ++c) a[c] = h1t[(size_t)c * 16384 + m];
  for (int dd = 0; dd < 32; ++dd) {
    const float4* w4 = (const float4*)(sW + (dd << 7));
    float s0 = 0.f, s1 = 0.f, s2 = 0.f, s3 = 0.f;
#pragma unroll
    for (int i = 0; i < 32; ++i) {
      const float4 w = w4[i];
      s0 = fmaf(w.x, a[4 * i], s0);
      s1 = fmaf(w.y, a[4 * i + 1], s1);
      s2 = fmaf(w.z, a[4 * i + 2], s2);
      s3 = fmaf(w.w, a[4 * i + 3], s3);
    }
    float v = fmaxf(0.0f, sb[dd] + ((s0 + s1) + (s2 + s3)));
    v = fmaxf(v, __shfl_xor(v, 1));
    v = fmaxf(v, __shfl_xor(v, 2));
    v = fmaxf(v, __shfl_xor(v, 4));
    v = fmaxf(v, __shfl_xor(v, 8));
    v = fmaxf(v, __shfl_xor(v, 16));
    v = fmaxf(v, __shfl_xor(v, 32));
    if (lane == 0) pmax[((size_t)(b << 3) + wc) * 256 + d0 + dd] = v;
  }
}

// ---------------------------------------------------------------------------
// K7: head. One block (1 wave) per batch. obj = max over 8 wave-partials,
// pose MLP + fusion MLP + two scalar heads.
// ---------------------------------------------------------------------------
__global__ __launch_bounds__(64) void k_head(
    const float* __restrict__ pmax, const float* __restrict__ grasp,
    const float* __restrict__ initp, const float* __restrict__ finalp,
    const int* __restrict__ surf, const float* __restrict__ embi,
    const float* __restrict__ embf, const float* __restrict__ pw0,
    const float* __restrict__ pb0, const float* __restrict__ pw1,
    const float* __restrict__ pb1, const float* __restrict__ pw2,
    const float* __restrict__ pb2, const float* __restrict__ fw0,
    const float* __restrict__ fb0, const float* __restrict__ fw1,
    const float* __restrict__ fb1, const float* __restrict__ osw,
    const float* __restrict__ osb, const float* __restrict__ ocw,
    const float* __restrict__ ocb, float* __restrict__ out) {
  __shared__ float obj[256], xb[37], A0[64], A1[128], A2[128], F0[128], HID[64];
  const int b = blockIdx.x, l = threadIdx.x;
  const float* pm = pmax + (size_t)b * 2048;
  for (int e = l; e < 256; e += 64) {
    float v = pm[e];
#pragma unroll
    for (int w = 1; w < 8; ++w) v = fmaxf(v, pm[w * 256 + e]);
    obj[e] = v;
  }
  if (l < 7) xb[l] = grasp[b * 7 + l];
  else if (l < 14) xb[l] = initp[b * 7 + l - 7];
  else if (l < 21) xb[l] = finalp[b * 7 + l - 14];
  else if (l < 29) xb[l] = embi[surf[b * 2] * 8 + l - 21];
  else if (l < 37) xb[l] = embf[surf[b * 2 + 1] * 8 + l - 29];
  __syncthreads();
  {
    float s = pb0[l];
    const float* wr = pw0 + l * 37;
#pragma unroll
    for (int c = 0; c < 37; ++c) s = fmaf(xb[c], wr[c], s);
    A0[l] = fmaxf(0.f, s);
  }
  __syncthreads();
#pragma unroll
  for (int dd = 0; dd < 2; ++dd) {
    const int d = l + dd * 64;
    float s = pb1[d];
    const float* wr = pw1 + d * 64;
#pragma unroll
    for (int c = 0; c < 64; ++c) s = fmaf(A0[c], wr[c], s);
    A1[d] = fmaxf(0.f, s);
  }
  __syncthreads();
#pragma unroll
  for (int dd = 0; dd < 2; ++dd) {
    const int d = l + dd * 64;
    float s = pb2[d];
    const float* wr = pw2 + d * 128;
#pragma unroll 16
    for (int c = 0; c < 128; ++c) s = fmaf(A1[c], wr[c], s);
    A2[d] = fmaxf(0.f, s);
  }
  __syncthreads();
#pragma unroll
  for (int dd = 0; dd < 2; ++dd) {
    const int d = l + dd * 64;
    float s = fb0[d];
    const float* wr = fw0 + d * 384;
#pragma unroll 16
    for (int c = 0; c < 256; ++c) s = fmaf(obj[c], wr[c], s);
#pragma unroll 16
    for (int c = 0; c < 128; ++c) s = fmaf(A2[c], wr[256 + c], s);
    F0[d] = fmaxf(0.f, s);
  }
  __syncthreads();
  {
    float s = fb1[l];
    const float* wr = fw1 + l * 128;
#pragma unroll 16
    for (int c = 0; c < 128; ++c) s = fmaf(F0[c], wr[c], s);
    HID[l] = fmaxf(0.f, s);
  }
  __syncthreads();
  float v1 = HID[l] * osw[l];
  float v2 = HID[l] * ocw[l];
#pragma unroll
  for (int off = 1; off < 64; off <<= 1) {
    v1 += __shfl_xor(v1, off);
    v2 += __shfl_xor(v2, off);
  }
  if (l == 0) {
    out[b] = v1 + osb[0];
    out[32 + b] = v2 + ocb[0];
  }
}

extern "C" void kernel_launch(void* const* d_in, const int* in_sizes, int n_in,
                              void* d_out, int out_size, void* d_ws, size_t ws_size,
                              hipStream_t stream) {
  const float* points  = (const float*)d_in[0];
  const float* grasp   = (const float*)d_in[1];
  const float* initp   = (const float*)d_in[2];
  const float* finalp  = (const float*)d_in[3];
  const int*   surf    = (const int*)d_in[4];
  const float* sa1_w0  = (const float*)d_in[5];
  const float* sa1_b0  = (const float*)d_in[6];
  const float* sa1_w1  = (const float*)d_in[7];
  const float* sa1_b1  = (const float*)d_in[8];
  const float* sa1_w2  = (const float*)d_in[9];
  const float* sa1_b2  = (const float*)d_in[10];
  const float* sa2_w0  = (const float*)d_in[11];
  const float* sa2_b0  = (const float*)d_in[12];
  const float* sa2_w1  = (const float*)d_in[13];
  const float* sa2_b1  = (const float*)d_in[14];
  const float* sa2_w2  = (const float*)d_in[15];
  const float* sa2_b2  = (const float*)d_in[16];
  const float* embi    = (const float*)d_in[17];
  const float* embf    = (const float*)d_in[18];
  const float* pe_w0   = (const float*)d_in[19];
  const float* pe_b0   = (const float*)d_in[20];
  const float* pe_w1   = (const float*)d_in[21];
  const float* pe_b1   = (const float*)d_in[22];
  const float* pe_w2   = (const float*)d_in[23];
  const float* pe_b2   = (const float*)d_in[24];
  const float* fu_w0   = (const float*)d_in[25];
  const float* fu_b0   = (const float*)d_in[26];
  const float* fu_w1   = (const float*)d_in[27];
  const float* fu_b1   = (const float*)d_in[28];
  const float* os_w    = (const float*)d_in[29];
  const float* os_b    = (const float*)d_in[30];
  const float* oc_w    = (const float*)d_in[31];
  const float* oc_b    = (const float*)d_in[32];

  char* ws = (char*)d_ws;
  // layout (bytes):
  int*   fidx    = (int*)(ws + 0);               //  65536
  float* new_xyz = (float*)(ws + 65536);         // 196608
  int*   gidx    = (int*)(ws + 262144);          // 2097152
  float* l1p     = (float*)(ws + 2359296);       // 8388608 (reused as h1t)
  float* h0t     = (float*)(ws + 10747904);      // 8388608
  float* pmax    = (float*)(ws + 19136512);      // 262144  -> end 19398656
  float* h1t     = l1p;  // l1_points dead after k_sa2_l0

  float* out = (float*)d_out;

  k_fps<<<32, 256, 0, stream>>>(points, fidx);
  k_ballq<<<4096, 256, 0, stream>>>(points, fidx, new_xyz, gidx);
  k_sa1<<<2048, 256, 0, stream>>>(points, new_xyz, gidx, sa1_w0, sa1_b0, sa1_w1,
                                  sa1_b1, sa1_w2, sa1_b2, l1p);
  k_sa2_l0<<<256, 256, 0, stream>>>(new_xyz, l1p, sa2_w0, sa2_b0, h0t);
  k_sa2_l1<<<256, 256, 0, stream>>>(h0t, sa2_w1, sa2_b1, h1t);
  k_sa2_l2max<<<512, 256, 0, stream>>>(h1t, sa2_w2, sa2_b2, pmax);
  k_head<<<32, 64, 0, stream>>>(pmax, grasp, initp, finalp, surf, embi, embf,
                                pe_w0, pe_b0, pe_w1, pe_b1, pe_w2, pe_b2, fu_w0,
                                fu_b0, fu_w1, fu_b1, os_w, os_b, oc_w, oc_b, out);
}

// Round 2
// 1068.949 us; speedup vs baseline: 1.2693x; 1.2693x over previous
//
#include <hip/hip_runtime.h>

#define DEVINL __device__ __forceinline__

// Exact (no-FMA-contraction) squared distance in the same rounding order as
// numpy/jax fp32: ((dx*dx + dy*dy) + dz*dz). Discrete decisions (FPS argmax,
// ball-query radius compare) depend on bit-exactness.
DEVINL float sq3(float ax, float ay, float az, float bx, float by, float bz) {
  float dx = __fsub_rn(ax, bx), dy = __fsub_rn(ay, by), dz = __fsub_rn(az, bz);
  return __fadd_rn(__fadd_rn(__fmul_rn(dx, dx), __fmul_rn(dy, dy)), __fmul_rn(dz, dz));
}

// ---------------------------------------------------------------------------
// K1: farthest point sampling. One block per batch (32), 256 threads.
// Points cached in registers (8/thread). Per step: reg-resident min-update,
// packed-u64-key argmax (val<<32 | 2047-idx: u64 max == first-occurrence
// argmax), single barrier with parity-double-buffered cross-wave exchange,
// redundant final reduce in every thread (no serial phase).
// ---------------------------------------------------------------------------
__global__ __launch_bounds__(256) void k_fps(const float* __restrict__ xyz,
                                             int* __restrict__ fidx) {
  const int b = blockIdx.x, t = threadIdx.x;
  __shared__ float xs[2048], ys[2048], zs[2048];
  __shared__ unsigned long long skey[2][4];
  const float* P = xyz + (size_t)b * 6144;
  for (int i = t; i < 2048; i += 256) {
    xs[i] = P[3 * i]; ys[i] = P[3 * i + 1]; zs[i] = P[3 * i + 2];
  }
  __syncthreads();
  float px[8], py[8], pz[8], dist[8];
#pragma unroll
  for (int j = 0; j < 8; ++j) {
    const int idx = j * 256 + t;
    px[j] = xs[idx]; py[j] = ys[idx]; pz[j] = zs[idx];
    dist[j] = 1e10f;
  }
  int far = 0;
  int* out = fidx + b * 512;
  for (int it = 0; it < 512; ++it) {
    if (t == 0) out[it] = far;  // emit BEFORE update (scan emits carry's far)
    const float cx = xs[far], cy = ys[far], cz = zs[far];
    float bv = -1.0f;
    int bi = 0;
#pragma unroll
    for (int j = 0; j < 8; ++j) {
      const float d = sq3(px[j], py[j], pz[j], cx, cy, cz);
      const float nd = fminf(dist[j], d);
      dist[j] = nd;
      if (nd > bv) { bv = nd; bi = j * 256 + t; }  // strict >: smallest idx kept
    }
    // packed key: larger value wins; tie -> larger (2047-idx) -> smaller idx
    unsigned long long key =
        ((unsigned long long)__float_as_uint(bv) << 32) | (unsigned)(2047 - bi);
#pragma unroll
    for (int off = 1; off < 64; off <<= 1) {
      const unsigned hi = __shfl_xor((unsigned)(key >> 32), off);
      const unsigned lo = __shfl_xor((unsigned)key, off);
      const unsigned long long ok = ((unsigned long long)hi << 32) | lo;
      key = (ok > key) ? ok : key;
    }
    const int par = it & 1;
    if ((t & 63) == 0) skey[par][t >> 6] = key;
    __syncthreads();
    unsigned long long k0 = skey[par][0], k1 = skey[par][1];
    unsigned long long k2 = skey[par][2], k3 = skey[par][3];
    k0 = (k1 > k0) ? k1 : k0;
    k2 = (k3 > k2) ? k3 : k2;
    k0 = (k2 > k0) ? k2 : k0;
    far = 2047 - (int)((unsigned)k0 & 2047u);
  }
}

// ---------------------------------------------------------------------------
// K2: ball query. One wave per centroid (16384 waves). Collect first 32
// ascending indices with d2 <= r^2; pad with first hit. Also writes new_xyz.
// ---------------------------------------------------------------------------
__global__ __launch_bounds__(256) void k_ballq(const float* __restrict__ xyz,
                                               const int* __restrict__ fidx,
                                               float* __restrict__ new_xyz,
                                               int* __restrict__ gidx) {
  const int gw = (blockIdx.x * 256 + threadIdx.x) >> 6;  // centroid id
  const int lane = threadIdx.x & 63;
  const int b = gw >> 9;
  const float* P = xyz + (size_t)b * 6144;
  const int cidx = fidx[gw];
  const float cx = P[3 * cidx], cy = P[3 * cidx + 1], cz = P[3 * cidx + 2];
  if (lane < 3) new_xyz[(size_t)gw * 3 + lane] = P[3 * cidx + lane];
  int* g = gidx + (size_t)gw * 32;
  int base = 0, firstidx = -1;
  for (int c0 = 0; c0 < 2048; c0 += 64) {
    const int idx = c0 + lane;
    const float d = sq3(cx, cy, cz, P[3 * idx], P[3 * idx + 1], P[3 * idx + 2]);
    const bool in = !(d > 0.04f);  // matches: exclude where sqr > r*r
    const unsigned long long m = __ballot(in);
    if (firstidx < 0 && m) firstidx = c0 + (int)__builtin_ctzll(m);
    if (in) {
      const int pos = base + (int)__popcll(m & ((1ull << lane) - 1ull));
      if (pos < 32) g[pos] = idx;
    }
    base += (int)__popcll(m);
    if (base >= 32) break;  // wave-uniform
  }
  for (int pos = base + lane; pos < 32; pos += 64) g[pos] = firstidx;
}

// ---------------------------------------------------------------------------
// K3: SA1 fused MLP (3->64->64->128) + max over 32 samples/group.
// lane = one grouped point; h0[64] regs; streaming d1-loop accumulates
// layer2 into acc[128] regs (all reg indices compile-time). Weights broadcast
// from LDS (uniform address => conflict-free broadcast reads).
// Block = 256 threads = 8 groups. Grid = 2048.
// ---------------------------------------------------------------------------
__global__ __launch_bounds__(256, 2) void k_sa1(
    const float* __restrict__ xyz, const float* __restrict__ new_xyz,
    const int* __restrict__ gidx, const float* __restrict__ w0,
    const float* __restrict__ b0, const float* __restrict__ w1,
    const float* __restrict__ b1, const float* __restrict__ w2,
    const float* __restrict__ b2, float* __restrict__ l1p) {
  __shared__ float sW0[64 * 4];    // packed row: w.x,w.y,w.z,bias
  __shared__ float sW1[64 * 64];   // row-major [d][c]
  __shared__ float sB1[64];
  __shared__ float sW2T[64 * 128];  // transposed [d1][e]
  __shared__ float sB2[128];
  const int t = threadIdx.x;
  for (int i = t; i < 64; i += 256) {
    sW0[4 * i] = w0[3 * i]; sW0[4 * i + 1] = w0[3 * i + 1];
    sW0[4 * i + 2] = w0[3 * i + 2]; sW0[4 * i + 3] = b0[i];
  }
  for (int i = t; i < 4096; i += 256) sW1[i] = w1[i];
  if (t < 64) sB1[t] = b1[t];
  for (int i = t; i < 8192; i += 256) sW2T[(i & 63) * 128 + (i >> 6)] = w2[i];
  if (t < 128) sB2[t] = b2[t];
  __syncthreads();
  const int p = blockIdx.x * 256 + t;  // global sample id
  const int g = p >> 5;                // group id = b*512+si
  const int b = p >> 14;
  const int lane = t & 63;
  const int src = gidx[p];
  const float* P = xyz + (size_t)b * 6144;
  const float nx = new_xyz[(size_t)g * 3], ny = new_xyz[(size_t)g * 3 + 1],
              nz = new_xyz[(size_t)g * 3 + 2];
  const float x = P[3 * src] - nx, y = P[3 * src + 1] - ny, z = P[3 * src + 2] - nz;
  float h0[64];
#pragma unroll
  for (int d = 0; d < 64; ++d) {
    const float4 w = ((const float4*)sW0)[d];
    h0[d] = fmaxf(0.0f, fmaf(w.x, x, fmaf(w.y, y, fmaf(w.z, z, w.w))));
  }
  float acc[128];
#pragma unroll
  for (int e4 = 0; e4 < 32; ++e4) {
    const float4 bb = ((const float4*)sB2)[e4];
    acc[4 * e4] = bb.x; acc[4 * e4 + 1] = bb.y;
    acc[4 * e4 + 2] = bb.z; acc[4 * e4 + 3] = bb.w;
  }
  for (int d1 = 0; d1 < 64; ++d1) {  // dynamic loop: layer1 scalar + layer2 rank-1 update
    const float4* wr = (const float4*)(sW1 + (d1 << 6));
    float s0 = 0.f, s1 = 0.f, s2 = 0.f, s3 = 0.f;
#pragma unroll
    for (int c4 = 0; c4 < 16; ++c4) {
      const float4 w = wr[c4];
      s0 = fmaf(w.x, h0[4 * c4], s0);
      s1 = fmaf(w.y, h0[4 * c4 + 1], s1);
      s2 = fmaf(w.z, h0[4 * c4 + 2], s2);
      s3 = fmaf(w.w, h0[4 * c4 + 3], s3);
    }
    const float s = fmaxf(0.0f, sB1[d1] + ((s0 + s1) + (s2 + s3)));
    const float4* w2r = (const float4*)(sW2T + (d1 << 7));
#pragma unroll
    for (int e4 = 0; e4 < 32; ++e4) {
      const float4 w = w2r[e4];
      acc[4 * e4] = fmaf(s, w.x, acc[4 * e4]);
      acc[4 * e4 + 1] = fmaf(s, w.y, acc[4 * e4 + 1]);
      acc[4 * e4 + 2] = fmaf(s, w.z, acc[4 * e4 + 2]);
      acc[4 * e4 + 3] = fmaf(s, w.w, acc[4 * e4 + 3]);
    }
  }
  // relu + max over each 32-lane half (one group) + predicated store
  float* outg = l1p + (size_t)g * 128;
#pragma unroll
  for (int e = 0; e < 128; ++e) {
    float v = fmaxf(0.0f, acc[e]);
    v = fmaxf(v, __shfl_xor(v, 1));
    v = fmaxf(v, __shfl_xor(v, 2));
    v = fmaxf(v, __shfl_xor(v, 4));
    v = fmaxf(v, __shfl_xor(v, 8));
    v = fmaxf(v, __shfl_xor(v, 16));
    if ((lane & 31) == (e & 31)) outg[e] = v;
  }
}

// ---------------------------------------------------------------------------
// SA2 layer kernels: lane = point (m), W chunk (32 output dims) staged in
// LDS, A row in registers. Outputs written transposed [d][m] (coalesced).
// ---------------------------------------------------------------------------
__global__ __launch_bounds__(256, 2) void k_sa2_l0(
    const float* __restrict__ new_xyz, const float* __restrict__ l1p,
    const float* __restrict__ w0, const float* __restrict__ b0,
    float* __restrict__ h0t) {
  __shared__ float sW[32 * 136];  // row: [0..2]=xyz w, [4..131]=feat w (16B aligned)
  __shared__ float sb[32];
  const int pb = blockIdx.x >> 2, ds = blockIdx.x & 3;
  const int t = threadIdx.x;
  const int d0 = ds * 32;
  for (int i = t; i < 32 * 131; i += 256) {
    const int r = i / 131, c = i - r * 131;
    const int dst = (c < 3) ? c : (c + 1);
    sW[r * 136 + dst] = w0[(size_t)(d0 + r) * 131 + c];
  }
  if (t < 32) sb[t] = b0[d0 + t];
  __syncthreads();
  const int m = pb * 256 + t;
  const float ax = new_xyz[(size_t)m * 3], ay = new_xyz[(size_t)m * 3 + 1],
              az = new_xyz[(size_t)m * 3 + 2];
  float4 av[32];
  const float4* lp = (const float4*)(l1p + (size_t)m * 128);
#pragma unroll
  for (int i = 0; i < 32; ++i) av[i] = lp[i];
  for (int dd = 0; dd < 32; ++dd) {
    const float* wr = sW + dd * 136;
    float s = fmaf(wr[0], ax, fmaf(wr[1], ay, fmaf(wr[2], az, sb[dd])));
    const float4* w4 = (const float4*)(wr + 4);
    float s0 = 0.f, s1 = 0.f, s2 = 0.f, s3 = 0.f;
#pragma unroll
    for (int i = 0; i < 32; ++i) {
      const float4 w = w4[i];
      s0 = fmaf(w.x, av[i].x, s0);
      s1 = fmaf(w.y, av[i].y, s1);
      s2 = fmaf(w.z, av[i].z, s2);
      s3 = fmaf(w.w, av[i].w, s3);
    }
    s += (s0 + s1) + (s2 + s3);
    h0t[(size_t)(d0 + dd) * 16384 + m] = fmaxf(0.0f, s);
  }
}

__global__ __launch_bounds__(256, 2) void k_sa2_l1(
    const float* __restrict__ h0t, const float* __restrict__ w1,
    const float* __restrict__ b1, float* __restrict__ h1t) {
  __shared__ float sW[32 * 128];
  __shared__ float sb[32];
  const int pb = blockIdx.x >> 2, ds = blockIdx.x & 3;
  const int t = threadIdx.x;
  const int d0 = ds * 32;
  for (int i = t; i < 32 * 128; i += 256) sW[i] = w1[(size_t)d0 * 128 + i];
  if (t < 32) sb[t] = b1[d0 + t];
  __syncthreads();
  const int m = pb * 256 + t;
  float a[128];
#pragma unroll
  for (int c = 0; c < 128; ++c) a[c] = h0t[(size_t)c * 16384 + m];
  for (int dd = 0; dd < 32; ++dd) {
    const float4* w4 = (const float4*)(sW + (dd << 7));
    float s0 = 0.f, s1 = 0.f, s2 = 0.f, s3 = 0.f;
#pragma unroll
    for (int i = 0; i < 32; ++i) {
      const float4 w = w4[i];
      s0 = fmaf(w.x, a[4 * i], s0);
      s1 = fmaf(w.y, a[4 * i + 1], s1);
      s2 = fmaf(w.z, a[4 * i + 2], s2);
      s3 = fmaf(w.w, a[4 * i + 3], s3);
    }
    h1t[(size_t)(d0 + dd) * 16384 + m] = fmaxf(0.0f, sb[dd] + ((s0 + s1) + (s2 + s3)));
  }
}

__global__ __launch_bounds__(256, 2) void k_sa2_l2max(
    const float* __restrict__ h1t, const float* __restrict__ w2,
    const float* __restrict__ b2, float* __restrict__ pmax) {
  __shared__ float sW[32 * 128];
  __shared__ float sb[32];
  const int pb = blockIdx.x >> 3, ds = blockIdx.x & 7;
  const int t = threadIdx.x;
  const int d0 = ds * 32;
  for (int i = t; i < 32 * 128; i += 256) sW[i] = w2[(size_t)d0 * 128 + i];
  if (t < 32) sb[t] = b2[d0 + t];
  __syncthreads();
  const int m = pb * 256 + t;
  const int b = m >> 9;
  const int wc = ((pb << 2) + (t >> 6)) & 7;  // wave-chunk within batch (0..7)
  const int lane = t & 63;
  float a[128];
#pragma unroll
  for (int c = 0; c < 128; ++c) a[c] = h1t[(size_t)c * 16384 + m];
  for (int dd = 0; dd < 32; ++dd) {
    const float4* w4 = (const float4*)(sW + (dd << 7));
    float s0 = 0.f, s1 = 0.f, s2 = 0.f, s3 = 0.f;
#pragma unroll
    for (int i = 0; i < 32; ++i) {
      const float4 w = w4[i];
      s0 = fmaf(w.x, a[4 * i], s0);
      s1 = fmaf(w.y, a[4 * i + 1], s1);
      s2 = fmaf(w.z, a[4 * i + 2], s2);
      s3 = fmaf(w.w, a[4 * i + 3], s3);
    }
    float v = fmaxf(0.0f, sb[dd] + ((s0 + s1) + (s2 + s3)));
    v = fmaxf(v, __shfl_xor(v, 1));
    v = fmaxf(v, __shfl_xor(v, 2));
    v = fmaxf(v, __shfl_xor(v, 4));
    v = fmaxf(v, __shfl_xor(v, 8));
    v = fmaxf(v, __shfl_xor(v, 16));
    v = fmaxf(v, __shfl_xor(v, 32));
    if (lane == 0) pmax[((size_t)(b << 3) + wc) * 256 + d0 + dd] = v;
  }
}

// ---------------------------------------------------------------------------
// K7: head. One block (1 wave) per batch. obj = max over 8 wave-partials,
// pose MLP + fusion MLP + two scalar heads.
// ---------------------------------------------------------------------------
__global__ __launch_bounds__(64) void k_head(
    const float* __restrict__ pmax, const float* __restrict__ grasp,
    const float* __restrict__ initp, const float* __restrict__ finalp,
    const int* __restrict__ surf, const float* __restrict__ embi,
    const float* __restrict__ embf, const float* __restrict__ pw0,
    const float* __restrict__ pb0, const float* __restrict__ pw1,
    const float* __restrict__ pb1, const float* __restrict__ pw2,
    const float* __restrict__ pb2, const float* __restrict__ fw0,
    const float* __restrict__ fb0, const float* __restrict__ fw1,
    const float* __restrict__ fb1, const float* __restrict__ osw,
    const float* __restrict__ osb, const float* __restrict__ ocw,
    const float* __restrict__ ocb, float* __restrict__ out) {
  __shared__ float obj[256], xb[37], A0[64], A1[128], A2[128], F0[128], HID[64];
  const int b = blockIdx.x, l = threadIdx.x;
  const float* pm = pmax + (size_t)b * 2048;
  for (int e = l; e < 256; e += 64) {
    float v = pm[e];
#pragma unroll
    for (int w = 1; w < 8; ++w) v = fmaxf(v, pm[w * 256 + e]);
    obj[e] = v;
  }
  if (l < 7) xb[l] = grasp[b * 7 + l];
  else if (l < 14) xb[l] = initp[b * 7 + l - 7];
  else if (l < 21) xb[l] = finalp[b * 7 + l - 14];
  else if (l < 29) xb[l] = embi[surf[b * 2] * 8 + l - 21];
  else if (l < 37) xb[l] = embf[surf[b * 2 + 1] * 8 + l - 29];
  __syncthreads();
  {
    float s = pb0[l];
    const float* wr = pw0 + l * 37;
#pragma unroll
    for (int c = 0; c < 37; ++c) s = fmaf(xb[c], wr[c], s);
    A0[l] = fmaxf(0.f, s);
  }
  __syncthreads();
#pragma unroll
  for (int dd = 0; dd < 2; ++dd) {
    const int d = l + dd * 64;
    float s = pb1[d];
    const float* wr = pw1 + d * 64;
#pragma unroll
    for (int c = 0; c < 64; ++c) s = fmaf(A0[c], wr[c], s);
    A1[d] = fmaxf(0.f, s);
  }
  __syncthreads();
#pragma unroll
  for (int dd = 0; dd < 2; ++dd) {
    const int d = l + dd * 64;
    float s = pb2[d];
    const float* wr = pw2 + d * 128;
#pragma unroll 16
    for (int c = 0; c < 128; ++c) s = fmaf(A1[c], wr[c], s);
    A2[d] = fmaxf(0.f, s);
  }
  __syncthreads();
#pragma unroll
  for (int dd = 0; dd < 2; ++dd) {
    const int d = l + dd * 64;
    float s = fb0[d];
    const float* wr = fw0 + d * 384;
#pragma unroll 16
    for (int c = 0; c < 256; ++c) s = fmaf(obj[c], wr[c], s);
#pragma unroll 16
    for (int c = 0; c < 128; ++c) s = fmaf(A2[c], wr[256 + c], s);
    F0[d] = fmaxf(0.f, s);
  }
  __syncthreads();
  {
    float s = fb1[l];
    const float* wr = fw1 + l * 128;
#pragma unroll 16
    for (int c = 0; c < 128; ++c) s = fmaf(F0[c], wr[c], s);
    HID[l] = fmaxf(0.f, s);
  }
  __syncthreads();
  float v1 = HID[l] * osw[l];
  float v2 = HID[l] * ocw[l];
#pragma unroll
  for (int off = 1; off < 64; off <<= 1) {
    v1 += __shfl_xor(v1, off);
    v2 += __shfl_xor(v2, off);
  }
  if (l == 0) {
    out[b] = v1 + osb[0];
    out[32 + b] = v2 + ocb[0];
  }
}

extern "C" void kernel_launch(void* const* d_in, const int* in_sizes, int n_in,
                              void* d_out, int out_size, void* d_ws, size_t ws_size,
                              hipStream_t stream) {
  const float* points  = (const float*)d_in[0];
  const float* grasp   = (const float*)d_in[1];
  const float* initp   = (const float*)d_in[2];
  const float* finalp  = (const float*)d_in[3];
  const int*   surf    = (const int*)d_in[4];
  const float* sa1_w0  = (const float*)d_in[5];
  const float* sa1_b0  = (const float*)d_in[6];
  const float* sa1_w1  = (const float*)d_in[7];
  const float* sa1_b1  = (const float*)d_in[8];
  const float* sa1_w2  = (const float*)d_in[9];
  const float* sa1_b2  = (const float*)d_in[10];
  const float* sa2_w0  = (const float*)d_in[11];
  const float* sa2_b0  = (const float*)d_in[12];
  const float* sa2_w1  = (const float*)d_in[13];
  const float* sa2_b1  = (const float*)d_in[14];
  const float* sa2_w2  = (const float*)d_in[15];
  const float* sa2_b2  = (const float*)d_in[16];
  const float* embi    = (const float*)d_in[17];
  const float* embf    = (const float*)d_in[18];
  const float* pe_w0   = (const float*)d_in[19];
  const float* pe_b0   = (const float*)d_in[20];
  const float* pe_w1   = (const float*)d_in[21];
  const float* pe_b1   = (const float*)d_in[22];
  const float* pe_w2   = (const float*)d_in[23];
  const float* pe_b2   = (const float*)d_in[24];
  const float* fu_w0   = (const float*)d_in[25];
  const float* fu_b0   = (const float*)d_in[26];
  const float* fu_w1   = (const float*)d_in[27];
  const float* fu_b1   = (const float*)d_in[28];
  const float* os_w    = (const float*)d_in[29];
  const float* os_b    = (const float*)d_in[30];
  const float* oc_w    = (const float*)d_in[31];
  const float* oc_b    = (const float*)d_in[32];

  char* ws = (char*)d_ws;
  // layout (bytes):
  int*   fidx    = (int*)(ws + 0);               //  65536
  float* new_xyz = (float*)(ws + 65536);         // 196608
  int*   gidx    = (int*)(ws + 262144);          // 2097152
  float* l1p     = (float*)(ws + 2359296);       // 8388608 (reused as h1t)
  float* h0t     = (float*)(ws + 10747904);      // 8388608
  float* pmax    = (float*)(ws + 19136512);      // 262144  -> end 19398656
  float* h1t     = l1p;  // l1_points dead after k_sa2_l0

  float* out = (float*)d_out;

  k_fps<<<32, 256, 0, stream>>>(points, fidx);
  k_ballq<<<4096, 256, 0, stream>>>(points, fidx, new_xyz, gidx);
  k_sa1<<<2048, 256, 0, stream>>>(points, new_xyz, gidx, sa1_w0, sa1_b0, sa1_w1,
                                  sa1_b1, sa1_w2, sa1_b2, l1p);
  k_sa2_l0<<<256, 256, 0, stream>>>(new_xyz, l1p, sa2_w0, sa2_b0, h0t);
  k_sa2_l1<<<256, 256, 0, stream>>>(h0t, sa2_w1, sa2_b1, h1t);
  k_sa2_l2max<<<512, 256, 0, stream>>>(h1t, sa2_w2, sa2_b2, pmax);
  k_head<<<32, 64, 0, stream>>>(pmax, grasp, initp, finalp, surf, embi, embf,
                                pe_w0, pe_b0, pe_w1, pe_b1, pe_w2, pe_b2, fu_w0,
                                fu_b0, fu_w1, fu_b1, os_w, os_b, oc_w, oc_b, out);
}